// Round 9
// baseline (150.633 us; speedup 1.0000x reference)
//
#include <hip/hip_runtime.h>
#include <hip/hip_bf16.h>
#include <stdint.h>

// BSpline KAN layer: out[b,o] = sum_{i,k} bases(tanh(x[b,i]))[k] * C[i,o,k]
// == GEMM M=8192, N=512, K=4096 with generated A. bf16 MFMA path.
// History:
//  R2/R8 84us: structurally different, identical counters => sum-of-demands.
//  R9 105us: proved pack VALU = 31us@x4 dup. R10 57.4us: materialized A
//      (pack once, 8us VALU) + pure GEMM. PMC: VALU 12, Mfma 24, HBM 34,
//      LDS port = 6144 b128 reads x12 + stage writes = ~71% busy => LDS-BOUND.
//      Reads set by reg reuse: 32rx64c waves = 0.75 reads/MFMA.
//  R11: 64x64 wave tiles (rm=cn=4) -> 0.5 reads/MFMA (reads 30.7->20.5us).
//      8-wave 512-thr block 128x128; waves 0-3 k<2048, waves 4-7 k>=2048
//      (two independent 2-deep pipelines, 4x16KB LDS bufs, f32 LDS-reduce).
//      BK=32/phase; new 64B-row involution C = S ^ ((R>>1)&3) (derived:
//      per-16-lane group covers all 8 granule slots -> 2-way = free).
//      XCD swizzle (p&7)*32+(p>>3): A-panel sharers co-locate per L2.
//      prep_bt+pack_a merged; launch_bounds(512,2) -> no VGPR squeeze.

typedef short s16x8 __attribute__((ext_vector_type(8)));   // 8 bf16
typedef float f32x4 __attribute__((ext_vector_type(4)));

#define BATCH 8192
#define IN_F  512
#define OUT_F 512
#define NB    8            // GRID_SIZE + SPLINE_ORDER
#define KKTOT (IN_F * NB)  // 4096
#define ROWB  (KKTOT * 2)  // 8192 B per row of Abf / BtT
#define NPH   64           // phases per K-group (2048 k / 32)

__device__ __forceinline__ uint32_t f2bf(float f) {
    union { float f; uint32_t u; } v; v.f = f;
    return (v.u + 0x7FFFu + ((v.u >> 16) & 1u)) >> 16;   // RNE bf16
}

__device__ __forceinline__ uint32_t bf16bits(float a) {
    __hip_bfloat16 h = __float2bfloat16(a);               // RNE
    union { __hip_bfloat16 h; unsigned short u; } c; c.h = h;
    return (uint32_t)c.u;
}

// 8 basis values for one x, packed bf16 into 16 bytes. Verified R0-R10.
__device__ __forceinline__ uint4 bspline_pack(float xraw) {
    float e  = __expf(2.0f * xraw);
    float xn = 1.0f - 2.0f / (e + 1.0f);          // tanh
    float u  = __fmaf_rn(xn, 2.5f, 5.5f);
    float fj = floorf(u);
    fj = fminf(fmaxf(fj, 3.0f), 7.0f);
    float t  = u - fj;
    float omt = 1.0f - t;
    float t2 = t * t;
    float t3 = t2 * t;
    const float s = 0.16666666666666666f;
    float w0 = s * omt * omt * omt;
    float w3 = s * t3;
    float w1 = s * __fmaf_rn(3.0f, t3, __fmaf_rn(-6.0f, t2, 4.0f));
    float w2 = 1.0f - w0 - w1 - w3;
    uint64_t packed = (uint64_t)(bf16bits(w0) | (bf16bits(w1) << 16))
                    | ((uint64_t)(bf16bits(w2) | (bf16bits(w3) << 16)) << 32);
    int sh = ((int)fj - 3) * 16;
    uint64_t lo, hi;
    if (sh == 0)      { lo = packed;       hi = 0ull; }
    else if (sh < 64) { lo = packed << sh; hi = packed >> (64 - sh); }
    else              { lo = 0ull;         hi = packed; }
    return make_uint4((uint32_t)lo, (uint32_t)(lo >> 32),
                      (uint32_t)hi, (uint32_t)(hi >> 32));
}

// Merged prep: blocks [0,1024) build BtT (verified prep_bt body);
// blocks [1024,5120) build Abf, 4 packs/thread (float4 in, 64 B out).
__global__ __launch_bounds__(256)
void prep_all(const float* __restrict__ X, const float* __restrict__ C,
              unsigned short* __restrict__ BtT, unsigned short* __restrict__ Abf) {
    if (blockIdx.x < 1024) {
        int t = blockIdx.x * 256 + threadIdx.x;
        int o = t & (OUT_F - 1);
        int i = t >> 9;
        const float4* src = (const float4*)(C + ((size_t)i * OUT_F + o) * NB);
        float4 c0 = src[0];
        float4 c1 = src[1];
        uint4 val;
        val.x = f2bf(c0.x) | (f2bf(c0.y) << 16);
        val.y = f2bf(c0.z) | (f2bf(c0.w) << 16);
        val.z = f2bf(c1.x) | (f2bf(c1.y) << 16);
        val.w = f2bf(c1.z) | (f2bf(c1.w) << 16);
        *(uint4*)(BtT + (size_t)o * KKTOT + (size_t)i * NB) = val;
    } else {
        int t  = (blockIdx.x - 1024) * 256 + threadIdx.x;  // 0..1,048,575
        int b  = t >> 7;                                   // row
        int ip = t & 127;                                  // group of 4 i's
        float4 xv = *(const float4*)(X + (size_t)b * IN_F + ip * 4);
        uint4 p0 = bspline_pack(xv.x);
        uint4 p1 = bspline_pack(xv.y);
        uint4 p2 = bspline_pack(xv.z);
        uint4 p3 = bspline_pack(xv.w);
        unsigned short* dst = Abf + (size_t)b * KKTOT + ip * 32;
        *(uint4*)(dst)      = p0;
        *(uint4*)(dst + 8)  = p1;
        *(uint4*)(dst + 16) = p2;
        *(uint4*)(dst + 24) = p3;
    }
}

__device__ __forceinline__ void gload_lds16(const void* g, void* l) {
    __builtin_amdgcn_global_load_lds(
        (const __attribute__((address_space(1))) uint32_t*)g,
        (__attribute__((address_space(3))) uint32_t*)l, 16, 0, 0);
}

// 128x128 block, 512 threads. Waves 0-3 (group 0): k in [0,2048);
// waves 4-7 (group 1): k in [2048,4096). Each wave: 64x64 output
// (rm=cn=4 of 16x16x32 frags). Per group: 2-deep LDS pipeline,
// 8 KB A-tile + 8 KB B-tile per buffer (BK=32). f32 reduce at end.
// LDS tile layout: granule G (16 B) holds row R=G>>2, slot S=G&3,
// containing global k-chunk C = S ^ ((R>>1)&3)  (involution, 2-way banks).
__global__ __launch_bounds__(512, 2)
void kan_gemm_mat2(const unsigned short* __restrict__ Abf,
                   const unsigned short* __restrict__ BtT,
                   float* __restrict__ Out) {
    __shared__ uint4 smem4[4096];                 // 64 KB
    char* smem = (char*)smem4;

    const int tid    = threadIdx.x;
    const int lane   = tid & 63;
    const int wv     = tid >> 6;     // 0..7
    const int gg     = wv >> 2;      // K-group
    const int w      = wv & 3;       // wave within group
    const int wr     = w >> 1;       // 64-row half
    const int wc     = w & 1;        // 64-col half
    const int lane16 = lane & 15;
    const int quad   = lane >> 4;

    // XCD swizzle: 256 blocks, xcd = p%8 gets 32 consecutive work ids
    // = 8 row-panels x 4 col-blocks -> A panel resident once per L2.
    const int work = (blockIdx.x & 7) * 32 + (blockIdx.x >> 3);
    const int row0 = (work >> 2) * 128;
    const int col0 = (work & 3) * 128;

    // ---- stage source addressing (pre-swizzled global, rule #21) ----
    // inst n of wave w covers granules G = w*128 + n*64 + lane:
    // R = G>>2 = w*32 + n*16 + (lane>>2); C = (lane&3) ^ ((lane>>3)&3).
    const int Cchunk = (lane & 3) ^ ((lane >> 3) & 3);
    const int R0 = w * 32 + (lane >> 2);          // n=0 row; n=1 adds 16
    const size_t gk = (size_t)gg * 4096;          // K-group byte offset in row
    const char* srcA0 = (const char*)Abf + (size_t)(row0 + R0) * ROWB + gk + Cchunk * 16;
    const char* srcA1 = srcA0 + (size_t)16 * ROWB;
    const char* srcB0 = (const char*)BtT + (size_t)(col0 + R0) * ROWB + gk + Cchunk * 16;
    const char* srcB1 = srcB0 + (size_t)16 * ROWB;
    const int wslot = w * 2048;                   // LDS byte base of inst n=0

    // ---- fragment read addressing ----
    // row/col = (wr|wc)*64 + f*16 + lane16; chunk quad^((row>>1)&3) and
    // (row>>1)&3 == (lane16>>1)&3 (all other offsets are 0 mod 8 rows).
    const int sx = (quad ^ ((lane16 >> 1) & 3)) << 4;
    const int abase = (wr * 64 + lane16) * 64 + sx;
    const int bbase = (wc * 64 + lane16) * 64 + sx;

    f32x4 acc[4][4] = {};

#define STAGE(B_, T_)                                                         \
    do {                                                                      \
        const size_t toff = (size_t)(T_) * 64;                                \
        char* la = smem + (gg * 2 + (B_)) * 16384 + wslot;                    \
        gload_lds16(srcA0 + toff, la);                                        \
        gload_lds16(srcA1 + toff, la + 1024);                                 \
        gload_lds16(srcB0 + toff, la + 8192);                                 \
        gload_lds16(srcB1 + toff, la + 8192 + 1024);                          \
    } while (0)

#define TILE(B_)                                                              \
    do {                                                                      \
        const char* ab = smem + (gg * 2 + (B_)) * 16384;                      \
        const char* bb = ab + 8192;                                           \
        s16x8 af0 = *(const s16x8*)(ab + abase);                              \
        s16x8 af1 = *(const s16x8*)(ab + abase + 1024);                       \
        s16x8 af2 = *(const s16x8*)(ab + abase + 2048);                       \
        s16x8 af3 = *(const s16x8*)(ab + abase + 3072);                       \
        s16x8 bf0 = *(const s16x8*)(bb + bbase);                              \
        s16x8 bf1 = *(const s16x8*)(bb + bbase + 1024);                       \
        s16x8 bf2 = *(const s16x8*)(bb + bbase + 2048);                       \
        s16x8 bf3 = *(const s16x8*)(bb + bbase + 3072);                       \
        acc[0][0] = __builtin_amdgcn_mfma_f32_16x16x32_bf16(af0, bf0, acc[0][0], 0, 0, 0); \
        acc[0][1] = __builtin_amdgcn_mfma_f32_16x16x32_bf16(af0, bf1, acc[0][1], 0, 0, 0); \
        acc[0][2] = __builtin_amdgcn_mfma_f32_16x16x32_bf16(af0, bf2, acc[0][2], 0, 0, 0); \
        acc[0][3] = __builtin_amdgcn_mfma_f32_16x16x32_bf16(af0, bf3, acc[0][3], 0, 0, 0); \
        acc[1][0] = __builtin_amdgcn_mfma_f32_16x16x32_bf16(af1, bf0, acc[1][0], 0, 0, 0); \
        acc[1][1] = __builtin_amdgcn_mfma_f32_16x16x32_bf16(af1, bf1, acc[1][1], 0, 0, 0); \
        acc[1][2] = __builtin_amdgcn_mfma_f32_16x16x32_bf16(af1, bf2, acc[1][2], 0, 0, 0); \
        acc[1][3] = __builtin_amdgcn_mfma_f32_16x16x32_bf16(af1, bf3, acc[1][3], 0, 0, 0); \
        acc[2][0] = __builtin_amdgcn_mfma_f32_16x16x32_bf16(af2, bf0, acc[2][0], 0, 0, 0); \
        acc[2][1] = __builtin_amdgcn_mfma_f32_16x16x32_bf16(af2, bf1, acc[2][1], 0, 0, 0); \
        acc[2][2] = __builtin_amdgcn_mfma_f32_16x16x32_bf16(af2, bf2, acc[2][2], 0, 0, 0); \
        acc[2][3] = __builtin_amdgcn_mfma_f32_16x16x32_bf16(af2, bf3, acc[2][3], 0, 0, 0); \
        acc[3][0] = __builtin_amdgcn_mfma_f32_16x16x32_bf16(af3, bf0, acc[3][0], 0, 0, 0); \
        acc[3][1] = __builtin_amdgcn_mfma_f32_16x16x32_bf16(af3, bf1, acc[3][1], 0, 0, 0); \
        acc[3][2] = __builtin_amdgcn_mfma_f32_16x16x32_bf16(af3, bf2, acc[3][2], 0, 0, 0); \
        acc[3][3] = __builtin_amdgcn_mfma_f32_16x16x32_bf16(af3, bf3, acc[3][3], 0, 0, 0); \
    } while (0)

    STAGE(0, 0);
    asm volatile("s_waitcnt vmcnt(0)" ::: "memory");
    __builtin_amdgcn_s_barrier();

    for (int t = 0; t < NPH; t += 2) {
        STAGE(1, t + 1);                      // t+1 <= 63 always
        TILE(0);
        asm volatile("s_waitcnt vmcnt(0)" ::: "memory");
        __builtin_amdgcn_s_barrier();
        if (t + 2 < NPH) STAGE(0, t + 2);
        TILE(1);
        asm volatile("s_waitcnt vmcnt(0)" ::: "memory");
        __builtin_amdgcn_s_barrier();
    }
#undef TILE
#undef STAGE

    // ---- cross-group K reduce via LDS (reuses staging space) ----
    f32x4* red = (f32x4*)smem + (size_t)w * 1024;    // 16 KB per wave pair
    if (gg == 1) {
        #pragma unroll
        for (int rm = 0; rm < 4; ++rm)
            #pragma unroll
            for (int cn = 0; cn < 4; ++cn)
                red[lane * 16 + rm * 4 + cn] = acc[rm][cn];
    }
    __builtin_amdgcn_s_barrier();
    if (gg == 0) {
        #pragma unroll
        for (int rm = 0; rm < 4; ++rm)
            #pragma unroll
            for (int cn = 0; cn < 4; ++cn)
                acc[rm][cn] += red[lane * 16 + rm * 4 + cn];
        // Epilogue: C/D layout col=lane&15, row=quad*4+reg (verified)
        #pragma unroll
        for (int rm = 0; rm < 4; ++rm) {
            const int orow = row0 + wr * 64 + rm * 16 + quad * 4;
            #pragma unroll
            for (int cn = 0; cn < 4; ++cn) {
                float* dst = Out + (size_t)orow * OUT_F
                           + col0 + wc * 64 + cn * 16 + lane16;
                #pragma unroll
                for (int r = 0; r < 4; ++r)
                    dst[(size_t)r * OUT_F] = acc[rm][cn][r];
            }
        }
    }
}

extern "C" void kernel_launch(void* const* d_in, const int* in_sizes, int n_in,
                              void* d_out, int out_size, void* d_ws, size_t ws_size,
                              hipStream_t stream) {
    const float* X  = (const float*)d_in[0];   // (8192, 512) f32
    const float* C  = (const float*)d_in[1];   // (512, 512, 8) f32
    float* Out = (float*)d_out;                // (8192, 512) f32

    unsigned short* BtT = (unsigned short*)d_ws;                       // 4 MB
    unsigned short* Abf = (unsigned short*)((char*)d_ws + (size_t)OUT_F * KKTOT * 2); // 64 MB
    // ws >= 68 MB confirmed empirically in R10 (mat path executed).

    prep_all<<<dim3(5120), 256, 0, stream>>>(X, C, BtT, Abf);
    kan_gemm_mat2<<<dim3(256), 512, 0, stream>>>(Abf, BtT, Out);
}

// Round 10
// 134.954 us; speedup vs baseline: 1.1162x; 1.1162x over previous
//
#include <hip/hip_runtime.h>
#include <hip/hip_bf16.h>
#include <stdint.h>

// BSpline KAN layer: out[b,o] = sum_{i,k} bases(tanh(x[b,i]))[k] * C[i,o,k]
// == GEMM M=8192, N=512, K=4096 with generated A. bf16 MFMA path.
// History:
//  R2/R8 84us: sum-of-demands at 2 waves/SIMD. R9: pack VALU isolated (31us).
//  R10 57.4us: materialize A once + pure GEMM (VALU 12, HBM 34, LDS ~71%).
//  R11 62.2us: 64x64 wave tiles halved LDS reads -> NO time change.
//      PMC: Mfma 20 / VALU 9 / HBM 13 / LDS ~44 / occ 18.9 (1 block/CU).
//      => per-phase vmcnt(0) drain (~60% of each phase) is the stall:
//      stage latency exposed, no co-resident block to fill it.
//      (1.9M bank conflicts = reduce indexing, 32-way, one-time.)
//  R12: counted-vmcnt deep pipeline (T3/T4, regime now matches):
//      4 bufs/group (128 KB LDS, m201-proven size), stage 3 phases ahead,
//      per phase: vmcnt(8) -> s_barrier -> STAGE(t+3) -> TILE(t).
//      Loads stay in flight ACROSS barriers; drain only in last 2 phases.
//      + setprio(1) around MFMA cluster (T5). + conflict-free reduce.
//      launch_bounds(512,1): no allocator squeeze possible.

typedef short s16x8 __attribute__((ext_vector_type(8)));   // 8 bf16
typedef float f32x4 __attribute__((ext_vector_type(4)));

#define BATCH 8192
#define IN_F  512
#define OUT_F 512
#define NB    8            // GRID_SIZE + SPLINE_ORDER
#define KKTOT (IN_F * NB)  // 4096
#define ROWB  (KKTOT * 2)  // 8192 B per row of Abf / BtT
#define NPH   64           // phases per K-group (2048 k / 32)

__device__ __forceinline__ uint32_t f2bf(float f) {
    union { float f; uint32_t u; } v; v.f = f;
    return (v.u + 0x7FFFu + ((v.u >> 16) & 1u)) >> 16;   // RNE bf16
}

__device__ __forceinline__ uint32_t bf16bits(float a) {
    __hip_bfloat16 h = __float2bfloat16(a);               // RNE
    union { __hip_bfloat16 h; unsigned short u; } c; c.h = h;
    return (uint32_t)c.u;
}

// 8 basis values for one x, packed bf16 into 16 bytes. Verified R0-R11.
__device__ __forceinline__ uint4 bspline_pack(float xraw) {
    float e  = __expf(2.0f * xraw);
    float xn = 1.0f - 2.0f / (e + 1.0f);          // tanh
    float u  = __fmaf_rn(xn, 2.5f, 5.5f);
    float fj = floorf(u);
    fj = fminf(fmaxf(fj, 3.0f), 7.0f);
    float t  = u - fj;
    float omt = 1.0f - t;
    float t2 = t * t;
    float t3 = t2 * t;
    const float s = 0.16666666666666666f;
    float w0 = s * omt * omt * omt;
    float w3 = s * t3;
    float w1 = s * __fmaf_rn(3.0f, t3, __fmaf_rn(-6.0f, t2, 4.0f));
    float w2 = 1.0f - w0 - w1 - w3;
    uint64_t packed = (uint64_t)(bf16bits(w0) | (bf16bits(w1) << 16))
                    | ((uint64_t)(bf16bits(w2) | (bf16bits(w3) << 16)) << 32);
    int sh = ((int)fj - 3) * 16;
    uint64_t lo, hi;
    if (sh == 0)      { lo = packed;       hi = 0ull; }
    else if (sh < 64) { lo = packed << sh; hi = packed >> (64 - sh); }
    else              { lo = 0ull;         hi = packed; }
    return make_uint4((uint32_t)lo, (uint32_t)(lo >> 32),
                      (uint32_t)hi, (uint32_t)(hi >> 32));
}

// Merged prep: blocks [0,1024) build BtT; blocks [1024,5120) build Abf.
// Verified R11.
__global__ __launch_bounds__(256)
void prep_all(const float* __restrict__ X, const float* __restrict__ C,
              unsigned short* __restrict__ BtT, unsigned short* __restrict__ Abf) {
    if (blockIdx.x < 1024) {
        int t = blockIdx.x * 256 + threadIdx.x;
        int o = t & (OUT_F - 1);
        int i = t >> 9;
        const float4* src = (const float4*)(C + ((size_t)i * OUT_F + o) * NB);
        float4 c0 = src[0];
        float4 c1 = src[1];
        uint4 val;
        val.x = f2bf(c0.x) | (f2bf(c0.y) << 16);
        val.y = f2bf(c0.z) | (f2bf(c0.w) << 16);
        val.z = f2bf(c1.x) | (f2bf(c1.y) << 16);
        val.w = f2bf(c1.z) | (f2bf(c1.w) << 16);
        *(uint4*)(BtT + (size_t)o * KKTOT + (size_t)i * NB) = val;
    } else {
        int t  = (blockIdx.x - 1024) * 256 + threadIdx.x;  // 0..1,048,575
        int b  = t >> 7;
        int ip = t & 127;
        float4 xv = *(const float4*)(X + (size_t)b * IN_F + ip * 4);
        uint4 p0 = bspline_pack(xv.x);
        uint4 p1 = bspline_pack(xv.y);
        uint4 p2 = bspline_pack(xv.z);
        uint4 p3 = bspline_pack(xv.w);
        unsigned short* dst = Abf + (size_t)b * KKTOT + ip * 32;
        *(uint4*)(dst)      = p0;
        *(uint4*)(dst + 8)  = p1;
        *(uint4*)(dst + 16) = p2;
        *(uint4*)(dst + 24) = p3;
    }
}

__device__ __forceinline__ void gload_lds16(const void* g, void* l) {
    __builtin_amdgcn_global_load_lds(
        (const __attribute__((address_space(1))) uint32_t*)g,
        (__attribute__((address_space(3))) uint32_t*)l, 16, 0, 0);
}

// 128x128 block, 512 threads. Waves 0-3: k in [0,2048); 4-7: [2048,4096).
// Each wave 64x64 (rm=cn=4). Per group: 4-buffer LDS pipeline staged 3
// phases ahead, counted vmcnt(8) per phase, drain only in tail.
// LDS tile layout (verified R11): granule G holds row R=G>>2, slot S=G&3,
// containing global k-chunk C = S ^ ((R>>1)&3) (involution, 2-way banks).
__global__ __launch_bounds__(512, 1)
void kan_gemm_mat2(const unsigned short* __restrict__ Abf,
                   const unsigned short* __restrict__ BtT,
                   float* __restrict__ Out) {
    __shared__ uint4 smem4[8192];                 // 128 KB (m201-proven size)
    char* smem = (char*)smem4;

    const int tid    = threadIdx.x;
    const int lane   = tid & 63;
    const int wv     = tid >> 6;     // 0..7
    const int gg     = wv >> 2;      // K-group
    const int w      = wv & 3;       // wave within group
    const int wr     = w >> 1;       // 64-row half
    const int wc     = w & 1;        // 64-col half
    const int lane16 = lane & 15;
    const int quad   = lane >> 4;

    // XCD swizzle (verified R11: FETCH 135->49 MB)
    const int work = (blockIdx.x & 7) * 32 + (blockIdx.x >> 3);
    const int row0 = (work >> 2) * 128;
    const int col0 = (work & 3) * 128;

    // stage source addressing (pre-swizzled global; verified R11)
    const int Cchunk = (lane & 3) ^ ((lane >> 3) & 3);
    const int R0 = w * 32 + (lane >> 2);
    const size_t gk = (size_t)gg * 4096;
    const char* srcA0 = (const char*)Abf + (size_t)(row0 + R0) * ROWB + gk + Cchunk * 16;
    const char* srcA1 = srcA0 + (size_t)16 * ROWB;
    const char* srcB0 = (const char*)BtT + (size_t)(col0 + R0) * ROWB + gk + Cchunk * 16;
    const char* srcB1 = srcB0 + (size_t)16 * ROWB;
    const int wslot = w * 2048;

    // fragment read addressing (verified R11)
    const int sx = (quad ^ ((lane16 >> 1) & 3)) << 4;
    const int abase = (wr * 64 + lane16) * 64 + sx;
    const int bbase = (wc * 64 + lane16) * 64 + sx;

    f32x4 acc[4][4] = {};

#define STAGE(B_, T_)                                                         \
    do {                                                                      \
        const size_t toff = (size_t)(T_) * 64;                                \
        char* la = smem + (gg * 4 + (B_)) * 16384 + wslot;                    \
        gload_lds16(srcA0 + toff, la);                                        \
        gload_lds16(srcA1 + toff, la + 1024);                                 \
        gload_lds16(srcB0 + toff, la + 8192);                                 \
        gload_lds16(srcB1 + toff, la + 8192 + 1024);                          \
    } while (0)

#define TILE(B_)                                                              \
    do {                                                                      \
        const char* ab = smem + (gg * 4 + (B_)) * 16384;                      \
        const char* bb = ab + 8192;                                           \
        s16x8 af0 = *(const s16x8*)(ab + abase);                              \
        s16x8 af1 = *(const s16x8*)(ab + abase + 1024);                       \
        s16x8 af2 = *(const s16x8*)(ab + abase + 2048);                       \
        s16x8 af3 = *(const s16x8*)(ab + abase + 3072);                       \
        s16x8 bf0 = *(const s16x8*)(bb + bbase);                              \
        s16x8 bf1 = *(const s16x8*)(bb + bbase + 1024);                       \
        s16x8 bf2 = *(const s16x8*)(bb + bbase + 2048);                       \
        s16x8 bf3 = *(const s16x8*)(bb + bbase + 3072);                       \
        __builtin_amdgcn_s_setprio(1);                                        \
        acc[0][0] = __builtin_amdgcn_mfma_f32_16x16x32_bf16(af0, bf0, acc[0][0], 0, 0, 0); \
        acc[0][1] = __builtin_amdgcn_mfma_f32_16x16x32_bf16(af0, bf1, acc[0][1], 0, 0, 0); \
        acc[0][2] = __builtin_amdgcn_mfma_f32_16x16x32_bf16(af0, bf2, acc[0][2], 0, 0, 0); \
        acc[0][3] = __builtin_amdgcn_mfma_f32_16x16x32_bf16(af0, bf3, acc[0][3], 0, 0, 0); \
        acc[1][0] = __builtin_amdgcn_mfma_f32_16x16x32_bf16(af1, bf0, acc[1][0], 0, 0, 0); \
        acc[1][1] = __builtin_amdgcn_mfma_f32_16x16x32_bf16(af1, bf1, acc[1][1], 0, 0, 0); \
        acc[1][2] = __builtin_amdgcn_mfma_f32_16x16x32_bf16(af1, bf2, acc[1][2], 0, 0, 0); \
        acc[1][3] = __builtin_amdgcn_mfma_f32_16x16x32_bf16(af1, bf3, acc[1][3], 0, 0, 0); \
        acc[2][0] = __builtin_amdgcn_mfma_f32_16x16x32_bf16(af2, bf0, acc[2][0], 0, 0, 0); \
        acc[2][1] = __builtin_amdgcn_mfma_f32_16x16x32_bf16(af2, bf1, acc[2][1], 0, 0, 0); \
        acc[2][2] = __builtin_amdgcn_mfma_f32_16x16x32_bf16(af2, bf2, acc[2][2], 0, 0, 0); \
        acc[2][3] = __builtin_amdgcn_mfma_f32_16x16x32_bf16(af2, bf3, acc[2][3], 0, 0, 0); \
        acc[3][0] = __builtin_amdgcn_mfma_f32_16x16x32_bf16(af3, bf0, acc[3][0], 0, 0, 0); \
        acc[3][1] = __builtin_amdgcn_mfma_f32_16x16x32_bf16(af3, bf1, acc[3][1], 0, 0, 0); \
        acc[3][2] = __builtin_amdgcn_mfma_f32_16x16x32_bf16(af3, bf2, acc[3][2], 0, 0, 0); \
        acc[3][3] = __builtin_amdgcn_mfma_f32_16x16x32_bf16(af3, bf3, acc[3][3], 0, 0, 0); \
        __builtin_amdgcn_s_setprio(0);                                        \
    } while (0)

// phase: wait own oldest 4 loads (t's tile), barrier, stage t+3, compute t.
// Buf[(t+3)%4] = buf[(t-1)%4]: its readers (TILE(t-1)) all passed this
// barrier -> WAR-safe. Loads for t+1,t+2 stay in flight across the barrier.
#define PHASE(B_, SB_, T_)                                                    \
    do {                                                                      \
        asm volatile("s_waitcnt vmcnt(8)" ::: "memory");                      \
        __builtin_amdgcn_s_barrier();                                         \
        STAGE(SB_, (T_) + 3);                                                 \
        TILE(B_);                                                             \
    } while (0)

    // prologue: 3 tiles in flight (12 loads/wave)
    STAGE(0, 0);
    STAGE(1, 1);
    STAGE(2, 2);

    for (int t = 0; t < NPH - 4; t += 4) {        // phases 0..59
        PHASE(0, 3, t + 0);
        PHASE(1, 0, t + 1);
        PHASE(2, 1, t + 2);
        PHASE(3, 2, t + 3);
    }
    // tail: phases 60..63 (stage 63 at phase 60; then drain down)
    asm volatile("s_waitcnt vmcnt(8)" ::: "memory");
    __builtin_amdgcn_s_barrier();
    STAGE(3, 63);
    TILE(0);
    asm volatile("s_waitcnt vmcnt(8)" ::: "memory");
    __builtin_amdgcn_s_barrier();
    TILE(1);
    asm volatile("s_waitcnt vmcnt(4)" ::: "memory");
    __builtin_amdgcn_s_barrier();
    TILE(2);
    asm volatile("s_waitcnt vmcnt(0)" ::: "memory");
    __builtin_amdgcn_s_barrier();
    TILE(3);
#undef PHASE
#undef TILE
#undef STAGE

    // ---- cross-group K reduce via LDS (conflict-free indexing: lane-major)
    __builtin_amdgcn_s_barrier();                 // all TILE reads done
    f32x4* red = (f32x4*)smem + (size_t)w * 1024; // 16 KB per wave pair
    if (gg == 1) {
        #pragma unroll
        for (int rm = 0; rm < 4; ++rm)
            #pragma unroll
            for (int cn = 0; cn < 4; ++cn)
                red[(rm * 4 + cn) * 64 + lane] = acc[rm][cn];
    }
    __builtin_amdgcn_s_barrier();
    if (gg == 0) {
        #pragma unroll
        for (int rm = 0; rm < 4; ++rm)
            #pragma unroll
            for (int cn = 0; cn < 4; ++cn)
                acc[rm][cn] += red[(rm * 4 + cn) * 64 + lane];
        // Epilogue: C/D layout col=lane&15, row=quad*4+reg (verified)
        #pragma unroll
        for (int rm = 0; rm < 4; ++rm) {
            const int orow = row0 + wr * 64 + rm * 16 + quad * 4;
            #pragma unroll
            for (int cn = 0; cn < 4; ++cn) {
                float* dst = Out + (size_t)orow * OUT_F
                           + col0 + wc * 64 + cn * 16 + lane16;
                #pragma unroll
                for (int r = 0; r < 4; ++r)
                    dst[(size_t)r * OUT_F] = acc[rm][cn][r];
            }
        }
    }
}

extern "C" void kernel_launch(void* const* d_in, const int* in_sizes, int n_in,
                              void* d_out, int out_size, void* d_ws, size_t ws_size,
                              hipStream_t stream) {
    const float* X  = (const float*)d_in[0];   // (8192, 512) f32
    const float* C  = (const float*)d_in[1];   // (512, 512, 8) f32
    float* Out = (float*)d_out;                // (8192, 512) f32

    unsigned short* BtT = (unsigned short*)d_ws;                                      // 4 MB
    unsigned short* Abf = (unsigned short*)((char*)d_ws + (size_t)OUT_F * KKTOT * 2); // 64 MB

    prep_all<<<dim3(5120), 256, 0, stream>>>(X, C, BtT, Abf);
    kan_gemm_mat2<<<dim3(256), 512, 0, stream>>>(Abf, BtT, Out);
}